// Round 8
// baseline (804.074 us; speedup 1.0000x reference)
//
#include <hip/hip_runtime.h>
#include <math.h>

#define NN 100000
#define NE 1600000
#define DI 256
#define DH 64
#define DO 47
#define NB ((NN + 255) / 256)       // 391 scan blocks
#define NRANGE 4                    // dst ranges for locality-phased fill
#define RSZ ((NN + NRANGE - 1) / NRANGE)      // 25000 nodes per range
#define EPB 2048                    // edges per fill block
#define CPB ((NE + EPB - 1) / EPB)  // 782 chunks per range
#define SB ((NN + 255) / 256)       // 391 block-groups per slice in sagg kernels

typedef float f8 __attribute__((ext_vector_type(8)));

// ---------------- degree (int atomics, deterministic) ----------------
__global__ __launch_bounds__(256) void k_degree(const int* __restrict__ dst,
                                                int* __restrict__ deg) {
    int e = blockIdx.x * 256 + threadIdx.x;
    if (e < NE) atomicAdd(&deg[dst[e]], 1);
}

// ---------------- scan pass 1: per-block sums of deg ----------------
__global__ __launch_bounds__(256) void k_part(const int* __restrict__ deg,
                                              int* __restrict__ part) {
    int i = blockIdx.x * 256 + threadIdx.x;
    int v = (i < NN) ? deg[i] : 0;
    for (int off = 32; off; off >>= 1) v += __shfl_xor(v, off);
    __shared__ int s[4];
    if ((threadIdx.x & 63) == 0) s[threadIdx.x >> 6] = v;
    __syncthreads();
    if (threadIdx.x == 0) part[blockIdx.x] = s[0] + s[1] + s[2] + s[3];
}

// ---------------- scan pass 2: exclusive scan of partials (NB<=512) ----------------
__global__ __launch_bounds__(512) void k_scanpart(int* __restrict__ part) {
    int t = threadIdx.x, lane = t & 63, wv = t >> 6;
    int v0 = (t < NB) ? part[t] : 0;
    int v = v0;
    for (int off = 1; off < 64; off <<= 1) {
        int u = __shfl_up(v, off);
        if (lane >= off) v += u;
    }
    __shared__ int ws[8];
    if (lane == 63) ws[wv] = v;
    __syncthreads();
    if (t == 0) {
        int run = 0;
        for (int w = 0; w < 8; ++w) { int tmp = ws[w]; ws[w] = run; run += tmp; }
    }
    __syncthreads();
    v += ws[wv];
    if (t < NB) part[t] = v - v0;   // exclusive
}

// ---------------- scan pass 3: prefix -> rowptr, cursor; fused dinv ----------------
__global__ __launch_bounds__(256) void k_scan3(const int* __restrict__ deg,
                                               const int* __restrict__ part,
                                               int* __restrict__ rowptr,
                                               int* __restrict__ cursor,
                                               float* __restrict__ dinv) {
    int i = blockIdx.x * 256 + threadIdx.x;
    int lane = threadIdx.x & 63, wv = threadIdx.x >> 6;
    int v0 = (i < NN) ? deg[i] : 0;
    int v = v0;
    for (int off = 1; off < 64; off <<= 1) {
        int u = __shfl_up(v, off);
        if (lane >= off) v += u;
    }
    __shared__ int ws[4], wo[4];
    if (lane == 63) ws[wv] = v;
    __syncthreads();
    if (threadIdx.x == 0) {
        int run = 0;
        for (int w = 0; w < 4; ++w) { int tmp = ws[w]; wo[w] = run; run += tmp; }
    }
    __syncthreads();
    int excl = part[blockIdx.x] + wo[wv] + v - v0;
    if (i < NN) {
        rowptr[i] = excl;
        cursor[i] = excl;
        dinv[i] = rsqrtf((float)(v0 + 1));
    }
}

// ---------------- range-phased bucket-fill ----------------
__global__ __launch_bounds__(256) void k_fillr(const int* __restrict__ src,
                                               const int* __restrict__ dst,
                                               int* __restrict__ cursor,
                                               int* __restrict__ csr_src) {
    int r = blockIdx.x / CPB;
    int chunk = blockIdx.x % CPB;
    int lo = r * RSZ, hi = lo + RSZ;   // [lo, hi)
    int base = chunk * EPB + threadIdx.x;
    #pragma unroll
    for (int i = 0; i < EPB / 256; ++i) {
        int e = base + i * 256;
        if (e < NE) {
            int d = dst[e];
            if (d >= lo && d < hi) {
                int p = atomicAdd(&cursor[d], 1);
                csr_src[p] = src[e];
            }
        }
    }
}

// ---------------- h1t[s][row][8] = dinv * (x @ W1), slab-major fp32 ----------------
// 512 threads, 64 rows/block, lane = row; wave w owns cols [8w,8w+8) = slab w.
__global__ __launch_bounds__(512) void k_gemm1(const float* __restrict__ x,
                                               const float* __restrict__ W1,
                                               const float* __restrict__ dinv,
                                               float* __restrict__ h1t) {
    __shared__ float xs[2][64 * 17];
    const int t = threadIdx.x;
    const int lane = t & 63;
    const int wvu = __builtin_amdgcn_readfirstlane(t >> 6);
    const int r0 = blockIdx.x * 64;
    const int sr = t >> 3;
    const int sk = (t & 7) * 2;
    const long xrow = (long)min(r0 + sr, NN - 1) * DI;
    const int row = r0 + lane;

    float acc[8] = {0.f, 0.f, 0.f, 0.f, 0.f, 0.f, 0.f, 0.f};

    {   // stage chunk 0
        float2 v = *(const float2*)(x + xrow + sk);
        xs[0][sr * 17 + sk] = v.x;
        xs[0][sr * 17 + sk + 1] = v.y;
    }
    __syncthreads();
    for (int c = 0; c < 16; ++c) {
        const int buf = c & 1;
        if (c + 1 < 16) {
            float2 v = *(const float2*)(x + xrow + (c + 1) * 16 + sk);
            xs[buf ^ 1][sr * 17 + sk] = v.x;
            xs[buf ^ 1][sr * 17 + sk + 1] = v.y;
        }
        const f8* wp = (const f8*)(W1) + (size_t)(c * 16) * (DH / 8) + wvu;
        #pragma unroll
        for (int k = 0; k < 16; ++k) {
            float xv = xs[buf][lane * 17 + k];
            f8 w8 = wp[(size_t)k * (DH / 8)];
            #pragma unroll
            for (int j = 0; j < 8; ++j) acc[j] += w8[j] * xv;
        }
        __syncthreads();
    }
    if (row < NN) {
        float di = dinv[row];
        float4 o0 = {di * acc[0], di * acc[1], di * acc[2], di * acc[3]};
        float4 o1 = {di * acc[4], di * acc[5], di * acc[6], di * acc[7]};
        float4* hp = (float4*)(h1t + ((size_t)wvu * NN + row) * 8);
        hp[0] = o0;
        hp[1] = o1;
    }
}

// ---------------- layer1 gather, XCD-pinned slabs ----------------
// slice s = blockIdx&7 (round-robin -> XCD s); slab = h1t[s] (3.2 MB, fits L2).
// Wave = 8 edges x 8 features. Writes h2t[s][row][f] = relu(di*(sum+self)+b1).
__global__ __launch_bounds__(256) void k_sagg1(const int* __restrict__ rowptr,
                                               const int* __restrict__ deg,
                                               const int* __restrict__ csr_src,
                                               const float* __restrict__ dinv,
                                               const float* __restrict__ h1t,
                                               const float* __restrict__ b1,
                                               float* __restrict__ h2t) {
    const int s = blockIdx.x & 7;
    const int bg = blockIdx.x >> 3;
    const float* __restrict__ slab = h1t + (size_t)s * NN * 8;
    float* __restrict__ oslab = h2t + (size_t)s * NN * 8;
    const int lane = threadIdx.x & 63, wv = threadIdx.x >> 6;
    const int e0 = lane >> 3, f = lane & 7;
    const float bias = b1[(s << 3) + f];
    const int wid = bg * 4 + wv;
    const int r0 = wid << 6;
    const int r1 = min(r0 + 64, NN);
    for (int row = r0; row < r1; ++row) {
        int beg = rowptr[row], cnt = deg[row];
        float acc = 0.f;
        for (int j = 0; j < cnt; j += 8) {
            int jj = j + e0;
            if (jj < cnt) {
                unsigned src = (unsigned)csr_src[beg + jj];
                acc += slab[src * 8u + f];
            }
        }
        acc += __shfl_xor(acc, 8);
        acc += __shfl_xor(acc, 16);
        acc += __shfl_xor(acc, 32);
        if (lane < 8) {
            float di = dinv[row];
            oslab[(unsigned)row * 8u + f] =
                fmaxf(di * (acc + slab[(unsigned)row * 8u + f]) + bias, 0.f);
        }
    }
}

// ---------------- GEMM2: h3t[s][row][6] = dinv * (h2 @ W2), slab-major ----------------
// 256 threads = 8 slab-groups x 32 rows. Reads h2t slabs, writes h3t slabs.
__global__ __launch_bounds__(256) void k_gemm2t(const float* __restrict__ h2t,
                                                const float* __restrict__ W2,
                                                const float* __restrict__ dinv,
                                                float* __restrict__ h3t) {
    __shared__ float w2[DH * DO];       // 12 KB
    __shared__ float sh[32][DH + 1];    // 8.3 KB
    for (int i = threadIdx.x; i < DH * DO; i += 256) w2[i] = W2[i];
    const int t = threadIdx.x;
    const int s = t >> 5, r = t & 31;
    const int row = blockIdx.x * 32 + r;      // NN % 32 == 0
    const float4* hp = (const float4*)(h2t + ((size_t)s * NN + row) * 8);
    float4 a = hp[0], b = hp[1];
    sh[r][s * 8 + 0] = a.x; sh[r][s * 8 + 1] = a.y;
    sh[r][s * 8 + 2] = a.z; sh[r][s * 8 + 3] = a.w;
    sh[r][s * 8 + 4] = b.x; sh[r][s * 8 + 5] = b.y;
    sh[r][s * 8 + 6] = b.z; sh[r][s * 8 + 7] = b.w;
    __syncthreads();
    float o[6] = {0.f, 0.f, 0.f, 0.f, 0.f, 0.f};
    #pragma unroll 4
    for (int k = 0; k < DH; ++k) {
        float hv = sh[r][k];
        #pragma unroll
        for (int fj = 0; fj < 6; ++fj) {
            int feat = 6 * s + fj;
            o[fj] += hv * w2[k * DO + (feat < DO ? feat : DO - 1)];
        }
    }
    float di = dinv[row];
    float* op = h3t + ((size_t)s * NN + row) * 6;
    #pragma unroll
    for (int fj = 0; fj < 6; ++fj) {
        int feat = 6 * s + fj;
        op[fj] = (feat < DO) ? di * o[fj] : 0.f;
    }
}

// ---------------- layer2 gather, XCD-pinned slabs (6 feats/slice) ----------------
// Writes xo[row][feat] = di*(sum+self)+b2 (row-major, final logits-input).
__global__ __launch_bounds__(256) void k_sagg2(const int* __restrict__ rowptr,
                                               const int* __restrict__ deg,
                                               const int* __restrict__ csr_src,
                                               const float* __restrict__ dinv,
                                               const float* __restrict__ h3t,
                                               const float* __restrict__ b2,
                                               float* __restrict__ xo) {
    const int s = blockIdx.x & 7;
    const int bg = blockIdx.x >> 3;
    const float* __restrict__ slab = h3t + (size_t)s * NN * 6;
    const int lane = threadIdx.x & 63, wv = threadIdx.x >> 6;
    const int e0 = lane >> 3, f = lane & 7;
    const int feat = s * 6 + f;
    const bool actf = (f < 6) && (feat < DO);
    const float bias = actf ? b2[feat] : 0.f;
    const int wid = bg * 4 + wv;
    const int r0 = wid << 6;
    const int r1 = min(r0 + 64, NN);
    for (int row = r0; row < r1; ++row) {
        int beg = rowptr[row], cnt = deg[row];
        float acc = 0.f;
        for (int j = 0; j < cnt; j += 8) {
            int jj = j + e0;
            if (jj < cnt && f < 6) {
                unsigned src = (unsigned)csr_src[beg + jj];
                acc += slab[src * 6u + f];
            }
        }
        acc += __shfl_xor(acc, 8);
        acc += __shfl_xor(acc, 16);
        acc += __shfl_xor(acc, 32);
        if (lane < 8 && actf) {
            float di = dinv[row];
            xo[(size_t)row * DO + feat] =
                di * (acc + slab[(unsigned)row * 6u + f]) + bias;
        }
    }
}

// ---------------- softmax + argmax from xo ----------------
__global__ __launch_bounds__(256) void k_soft(const float* __restrict__ xo,
                                              float* __restrict__ logits,
                                              float* __restrict__ preds) {
    int wv = threadIdx.x >> 6, lane = threadIdx.x & 63;
    int row = blockIdx.x * 4 + wv;
    bool act = lane < DO;
    float val = act ? xo[(size_t)row * DO + lane] : -INFINITY;
    float m = val;
    for (int off = 32; off; off >>= 1) m = fmaxf(m, __shfl_xor(m, off));
    int idx = (act && val == m) ? lane : (1 << 30);
    for (int off = 32; off; off >>= 1) idx = min(idx, __shfl_xor(idx, off));
    float ev = act ? expf(val - m) : 0.f;
    float ssum = ev;
    for (int off = 32; off; off >>= 1) ssum += __shfl_xor(ssum, off);
    if (act) logits[(size_t)row * DO + lane] = ev / ssum;
    if (lane == 0) preds[row] = (float)idx;
}

extern "C" void kernel_launch(void* const* d_in, const int* in_sizes, int n_in,
                              void* d_out, int out_size, void* d_ws, size_t ws_size,
                              hipStream_t stream) {
    const float* x  = (const float*)d_in[0];
    const int*   ei = (const int*)d_in[1];
    const float* W1 = (const float*)d_in[2];
    const float* b1 = (const float*)d_in[3];
    const float* W2 = (const float*)d_in[4];
    const float* b2 = (const float*)d_in[5];
    const int* src = ei;          // edge_index[0]
    const int* dst = ei + NE;     // edge_index[1]

    float* out    = (float*)d_out;
    float* logits = out;                      // [N,47]
    float* preds  = out + (size_t)NN * DO;    // [N]
    float* xo     = preds + NN;               // [N,47]

    // workspace (~59 MB): h3t aliases h1t (dead after k_sagg1)
    char* wsb = (char*)d_ws;
    int*   deg     = (int*)wsb;                         wsb += (size_t)NN * 4;
    float* dinv    = (float*)wsb;                       wsb += (size_t)NN * 4;
    int*   rowptr  = (int*)wsb;                         wsb += (size_t)NN * 4;
    int*   cursor  = (int*)wsb;                         wsb += (size_t)NN * 4;
    int*   part    = (int*)wsb;                         wsb += (size_t)512 * 4;
    int*   csr_src = (int*)wsb;                         wsb += (size_t)NE * 4;
    float* h1t     = (float*)wsb;                       wsb += (size_t)NN * DH * 4;
    float* h2t     = (float*)wsb;                       wsb += (size_t)NN * DH * 4;
    float* h3t     = h1t;   // [8][NN][6] = NN*48 floats <= NN*64 ✓

    hipMemsetAsync(deg, 0, NN * sizeof(int), stream);

    k_degree<<<(NE + 255) / 256, 256, 0, stream>>>(dst, deg);
    k_part<<<NB, 256, 0, stream>>>(deg, part);
    k_scanpart<<<1, 512, 0, stream>>>(part);
    k_scan3<<<NB, 256, 0, stream>>>(deg, part, rowptr, cursor, dinv);
    k_fillr<<<NRANGE * CPB, 256, 0, stream>>>(src, dst, cursor, csr_src);
    k_gemm1<<<(NN + 63) / 64, 512, 0, stream>>>(x, W1, dinv, h1t);
    k_sagg1<<<8 * SB, 256, 0, stream>>>(rowptr, deg, csr_src, dinv, h1t, b1, h2t);
    k_gemm2t<<<NN / 32, 256, 0, stream>>>(h2t, W2, dinv, h3t);
    k_sagg2<<<8 * SB, 256, 0, stream>>>(rowptr, deg, csr_src, dinv, h3t, b2, xo);
    k_soft<<<NN / 4, 256, 0, stream>>>(xo, logits, preds);
}

// Round 9
// 363.521 us; speedup vs baseline: 2.2119x; 2.2119x over previous
//
#include <hip/hip_runtime.h>
#include <math.h>

#define NN 100000
#define NE 1600000
#define DI 256
#define DH 64
#define DO 47
#define DH3 48                      // h3s row stride: 192B -> 19.2 MB footprint
#define NB ((NN + 255) / 256)       // 391 scan blocks
#define NRANGE 4                    // dst ranges for locality-phased fill
#define RSZ ((NN + NRANGE - 1) / NRANGE)      // 25000 nodes per range
#define EPB 2048                    // edges per fill block
#define CPB ((NE + EPB - 1) / EPB)  // 782 chunks per range

typedef float f8 __attribute__((ext_vector_type(8)));

// ---------------- degree (int atomics, deterministic) ----------------
__global__ __launch_bounds__(256) void k_degree(const int* __restrict__ dst,
                                                int* __restrict__ deg) {
    int e = blockIdx.x * 256 + threadIdx.x;
    if (e < NE) atomicAdd(&deg[dst[e]], 1);
}

// ---------------- scan pass 1: per-block sums of deg ----------------
__global__ __launch_bounds__(256) void k_part(const int* __restrict__ deg,
                                              int* __restrict__ part) {
    int i = blockIdx.x * 256 + threadIdx.x;
    int v = (i < NN) ? deg[i] : 0;
    for (int off = 32; off; off >>= 1) v += __shfl_xor(v, off);
    __shared__ int s[4];
    if ((threadIdx.x & 63) == 0) s[threadIdx.x >> 6] = v;
    __syncthreads();
    if (threadIdx.x == 0) part[blockIdx.x] = s[0] + s[1] + s[2] + s[3];
}

// ---------------- scan pass 2: exclusive scan of partials (NB<=512) ----------------
__global__ __launch_bounds__(512) void k_scanpart(int* __restrict__ part) {
    int t = threadIdx.x, lane = t & 63, wv = t >> 6;
    int v0 = (t < NB) ? part[t] : 0;
    int v = v0;
    for (int off = 1; off < 64; off <<= 1) {
        int u = __shfl_up(v, off);
        if (lane >= off) v += u;
    }
    __shared__ int ws[8];
    if (lane == 63) ws[wv] = v;
    __syncthreads();
    if (t == 0) {
        int run = 0;
        for (int w = 0; w < 8; ++w) { int tmp = ws[w]; ws[w] = run; run += tmp; }
    }
    __syncthreads();
    v += ws[wv];
    if (t < NB) part[t] = v - v0;   // exclusive
}

// ---------------- scan pass 3: prefix -> rowptr, cursor; fused dinv ----------------
__global__ __launch_bounds__(256) void k_scan3(const int* __restrict__ deg,
                                               const int* __restrict__ part,
                                               int* __restrict__ rowptr,
                                               int* __restrict__ cursor,
                                               float* __restrict__ dinv) {
    int i = blockIdx.x * 256 + threadIdx.x;
    int lane = threadIdx.x & 63, wv = threadIdx.x >> 6;
    int v0 = (i < NN) ? deg[i] : 0;
    int v = v0;
    for (int off = 1; off < 64; off <<= 1) {
        int u = __shfl_up(v, off);
        if (lane >= off) v += u;
    }
    __shared__ int ws[4], wo[4];
    if (lane == 63) ws[wv] = v;
    __syncthreads();
    if (threadIdx.x == 0) {
        int run = 0;
        for (int w = 0; w < 4; ++w) { int tmp = ws[w]; wo[w] = run; run += tmp; }
    }
    __syncthreads();
    int excl = part[blockIdx.x] + wo[wv] + v - v0;
    if (i < NN) {
        rowptr[i] = excl;
        cursor[i] = excl;
        dinv[i] = rsqrtf((float)(v0 + 1));
    }
}

// ---------------- range-phased bucket-fill ----------------
__global__ __launch_bounds__(256) void k_fillr(const int* __restrict__ src,
                                               const int* __restrict__ dst,
                                               int* __restrict__ cursor,
                                               int* __restrict__ csr_src) {
    int r = blockIdx.x / CPB;
    int chunk = blockIdx.x % CPB;
    int lo = r * RSZ, hi = lo + RSZ;   // [lo, hi)
    int base = chunk * EPB + threadIdx.x;
    #pragma unroll
    for (int i = 0; i < EPB / 256; ++i) {
        int e = base + i * 256;
        if (e < NE) {
            int d = dst[e];
            if (d >= lo && d < hi) {
                int p = atomicAdd(&cursor[d], 1);
                csr_src[p] = src[e];
            }
        }
    }
}

// ---------------- h1s = dinv * (x @ W1)  (N x 256 x 64), fp32 ----------------
__global__ __launch_bounds__(512) void k_gemm1(const float* __restrict__ x,
                                               const float* __restrict__ W1,
                                               const float* __restrict__ dinv,
                                               float* __restrict__ h1s) {
    __shared__ float xs[2][64 * 17];
    const int t = threadIdx.x;
    const int lane = t & 63;
    const int wvu = __builtin_amdgcn_readfirstlane(t >> 6);
    const int r0 = blockIdx.x * 64;
    const int sr = t >> 3;
    const int sk = (t & 7) * 2;
    const long xrow = (long)min(r0 + sr, NN - 1) * DI;
    const int row = r0 + lane;

    float acc[8] = {0.f, 0.f, 0.f, 0.f, 0.f, 0.f, 0.f, 0.f};

    {   // stage chunk 0
        float2 v = *(const float2*)(x + xrow + sk);
        xs[0][sr * 17 + sk] = v.x;
        xs[0][sr * 17 + sk + 1] = v.y;
    }
    __syncthreads();
    for (int c = 0; c < 16; ++c) {
        const int buf = c & 1;
        if (c + 1 < 16) {
            float2 v = *(const float2*)(x + xrow + (c + 1) * 16 + sk);
            xs[buf ^ 1][sr * 17 + sk] = v.x;
            xs[buf ^ 1][sr * 17 + sk + 1] = v.y;
        }
        const f8* wp = (const f8*)(W1) + (size_t)(c * 16) * (DH / 8) + wvu;
        #pragma unroll
        for (int k = 0; k < 16; ++k) {
            float xv = xs[buf][lane * 17 + k];
            f8 w8 = wp[(size_t)k * (DH / 8)];
            #pragma unroll
            for (int j = 0; j < 8; ++j) acc[j] += w8[j] * xv;
        }
        __syncthreads();
    }
    if (row < NN) {
        float di = dinv[row];
        float4 o0 = {di * acc[0], di * acc[1], di * acc[2], di * acc[3]};
        float4 o1 = {di * acc[4], di * acc[5], di * acc[6], di * acc[7]};
        float4* hp = (float4*)(h1s + (long)row * DH + wvu * 8);
        hp[0] = o0;
        hp[1] = o1;
    }
}

// ---------------- layer1 gather (2 rows/wave) + relu/bias + GEMM2 fused ----------------
// Each wave owns rows rA,rB; joint clamped-masked loop keeps 8 h1s gathers +
// 8 csr loads in flight (2x round-7 MLP). agg = di*(sum + self); h2=relu(agg+b1);
// h3s = di*(h2@W2), stride DH3.
__global__ __launch_bounds__(256) void k_agg1(const int* __restrict__ rowptr,
                                              const int* __restrict__ deg,
                                              const int* __restrict__ csr_src,
                                              const float* __restrict__ dinv,
                                              const float* __restrict__ h1s,
                                              const float* __restrict__ b1,
                                              const float* __restrict__ W2,
                                              float* __restrict__ h3s) {
    __shared__ float w2[DH * DO];   // 12 KB
    __shared__ float sh[8][DH];     // 2 KB
    for (int i = threadIdx.x; i < DH * DO; i += 256) w2[i] = W2[i];
    __syncthreads();
    const int wv = threadIdx.x >> 6, lane = threadIdx.x & 63;
    const int rA = blockIdx.x * 8 + wv * 2;
    const int rB = rA + 1;
    const int begA = rowptr[rA], cntA = deg[rA];
    const int begB = rowptr[rB], cntB = deg[rB];
    float accA = 0.f, accB = 0.f;
    const int tmax = max(cntA, cntB);
    #pragma unroll 2
    for (int j = 0; j < tmax; j += 4) {
        #pragma unroll
        for (int k = 0; k < 4; ++k) {
            int sa = csr_src[min(begA + j + k, NE - 1)];
            int sb = csr_src[min(begB + j + k, NE - 1)];
            float va = h1s[(size_t)sa * DH + lane];
            float vb = h1s[(size_t)sb * DH + lane];
            accA += (j + k < cntA) ? va : 0.f;
            accB += (j + k < cntB) ? vb : 0.f;
        }
    }
    const float diA = dinv[rA], diB = dinv[rB];
    float vA = diA * (accA + h1s[(size_t)rA * DH + lane]) + b1[lane];
    float vB = diB * (accB + h1s[(size_t)rB * DH + lane]) + b1[lane];
    sh[wv * 2 + 0][lane] = fmaxf(vA, 0.f);
    sh[wv * 2 + 1][lane] = fmaxf(vB, 0.f);
    __syncthreads();
    if (lane < DO) {
        float oA = 0.f, oB = 0.f;
        #pragma unroll 8
        for (int k = 0; k < DH; ++k) {
            float w = w2[k * DO + lane];
            oA += sh[wv * 2 + 0][k] * w;
            oB += sh[wv * 2 + 1][k] * w;
        }
        h3s[(size_t)rA * DH3 + lane] = diA * oA;
        h3s[(size_t)rB * DH3 + lane] = diB * oB;
    }
}

// ---------------- layer2 gather (2 rows/wave) + softmax/argmax fused ----------------
__global__ __launch_bounds__(256) void k_agg2(const int* __restrict__ rowptr,
                                              const int* __restrict__ deg,
                                              const int* __restrict__ csr_src,
                                              const float* __restrict__ dinv,
                                              const float* __restrict__ h3s,
                                              const float* __restrict__ b2,
                                              float* __restrict__ logits,
                                              float* __restrict__ preds,
                                              float* __restrict__ xo) {
    const int wv = threadIdx.x >> 6, lane = threadIdx.x & 63;
    const int rA = blockIdx.x * 8 + wv * 2;
    const int rB = rA + 1;
    const int begA = rowptr[rA], cntA = deg[rA];
    const int begB = rowptr[rB], cntB = deg[rB];
    const bool act = lane < DO;
    const int lx = act ? lane : 0;
    float accA = 0.f, accB = 0.f;
    const int tmax = max(cntA, cntB);
    #pragma unroll 2
    for (int j = 0; j < tmax; j += 4) {
        #pragma unroll
        for (int k = 0; k < 4; ++k) {
            int sa = csr_src[min(begA + j + k, NE - 1)];
            int sb = csr_src[min(begB + j + k, NE - 1)];
            float va = h3s[(size_t)sa * DH3 + lx];
            float vb = h3s[(size_t)sb * DH3 + lx];
            accA += (j + k < cntA) ? va : 0.f;
            accB += (j + k < cntB) ? vb : 0.f;
        }
    }
    const float diA = dinv[rA], diB = dinv[rB];
    float valA = -INFINITY, valB = -INFINITY;
    if (act) {
        valA = diA * (accA + h3s[(size_t)rA * DH3 + lane]) + b2[lane];
        valB = diB * (accB + h3s[(size_t)rB * DH3 + lane]) + b2[lane];
        xo[(size_t)rA * DO + lane] = valA;
        xo[(size_t)rB * DO + lane] = valB;
    }
    float mA = valA, mB = valB;
    for (int off = 32; off; off >>= 1) {
        mA = fmaxf(mA, __shfl_xor(mA, off));
        mB = fmaxf(mB, __shfl_xor(mB, off));
    }
    int idxA = (act && valA == mA) ? lane : (1 << 30);
    int idxB = (act && valB == mB) ? lane : (1 << 30);
    for (int off = 32; off; off >>= 1) {
        idxA = min(idxA, __shfl_xor(idxA, off));
        idxB = min(idxB, __shfl_xor(idxB, off));
    }
    float evA = act ? expf(valA - mA) : 0.f;
    float evB = act ? expf(valB - mB) : 0.f;
    float sA = evA, sB = evB;
    for (int off = 32; off; off >>= 1) {
        sA += __shfl_xor(sA, off);
        sB += __shfl_xor(sB, off);
    }
    if (act) {
        logits[(size_t)rA * DO + lane] = evA / sA;
        logits[(size_t)rB * DO + lane] = evB / sB;
    }
    if (lane == 0) {
        preds[rA] = (float)idxA;
        preds[rB] = (float)idxB;
    }
}

extern "C" void kernel_launch(void* const* d_in, const int* in_sizes, int n_in,
                              void* d_out, int out_size, void* d_ws, size_t ws_size,
                              hipStream_t stream) {
    const float* x  = (const float*)d_in[0];
    const int*   ei = (const int*)d_in[1];
    const float* W1 = (const float*)d_in[2];
    const float* b1 = (const float*)d_in[3];
    const float* W2 = (const float*)d_in[4];
    const float* b2 = (const float*)d_in[5];
    const int* src = ei;          // edge_index[0]
    const int* dst = ei + NE;     // edge_index[1]

    float* out    = (float*)d_out;
    float* logits = out;                      // [N,47]
    float* preds  = out + (size_t)NN * DO;    // [N]
    float* xo     = preds + NN;               // [N,47]

    // workspace layout (~53 MB)
    char* wsb = (char*)d_ws;
    int*   deg     = (int*)wsb;                         wsb += (size_t)NN * 4;
    float* dinv    = (float*)wsb;                       wsb += (size_t)NN * 4;
    int*   rowptr  = (int*)wsb;                         wsb += (size_t)NN * 4;
    int*   cursor  = (int*)wsb;                         wsb += (size_t)NN * 4;
    int*   part    = (int*)wsb;                         wsb += (size_t)512 * 4;
    int*   csr_src = (int*)wsb;                         wsb += (size_t)NE * 4;
    float* h1s     = (float*)wsb;                       wsb += (size_t)NN * DH * 4;
    float* h3s     = (float*)wsb;                       wsb += (size_t)NN * DH3 * 4;

    hipMemsetAsync(deg, 0, NN * sizeof(int), stream);

    k_degree<<<(NE + 255) / 256, 256, 0, stream>>>(dst, deg);
    k_part<<<NB, 256, 0, stream>>>(deg, part);
    k_scanpart<<<1, 512, 0, stream>>>(part);
    k_scan3<<<NB, 256, 0, stream>>>(deg, part, rowptr, cursor, dinv);
    k_fillr<<<NRANGE * CPB, 256, 0, stream>>>(src, dst, cursor, csr_src);
    k_gemm1<<<(NN + 63) / 64, 512, 0, stream>>>(x, W1, dinv, h1s);
    k_agg1<<<NN / 8, 256, 0, stream>>>(rowptr, deg, csr_src, dinv, h1s, b1, W2, h3s);
    k_agg2<<<NN / 8, 256, 0, stream>>>(rowptr, deg, csr_src, dinv, h3s, b2, logits, preds, xo);
}

// Round 10
// 347.000 us; speedup vs baseline: 2.3172x; 1.0476x over previous
//
#include <hip/hip_runtime.h>
#include <math.h>

#define NN 100000
#define NE 1600000
#define DI 256
#define DH 64
#define DO 47
#define DH3 48                      // h3s row stride: 192B -> 19.2 MB footprint
#define NB ((NN + 255) / 256)       // 391 scan blocks
#define RSZ8 ((NN + 7) / 8)         // 12500 nodes per XCD-pinned range
#define EPB 2048                    // edges per fill block
#define CPB ((NE + EPB - 1) / EPB)  // 782 chunks per range

typedef float f8 __attribute__((ext_vector_type(8)));

// ---------------- degree, XCD-pinned ranges ----------------
// r = blockIdx&7 -> XCD r (round-robin mapping, validated round 8). Each XCD
// only touches deg[lo,hi): 50 KB, L2-resident, written back once.
__global__ __launch_bounds__(256) void k_degree(const int* __restrict__ dst,
                                                int* __restrict__ deg) {
    int r = blockIdx.x & 7;
    int chunk = blockIdx.x >> 3;
    int lo = r * RSZ8, hi = min(lo + RSZ8, NN);
    int base = chunk * EPB + threadIdx.x;
    #pragma unroll
    for (int i = 0; i < EPB / 256; ++i) {
        int e = base + i * 256;
        if (e < NE) {
            int d = dst[e];
            if (d >= lo && d < hi) atomicAdd(&deg[d], 1);
        }
    }
}

// ---------------- scan pass 1: per-block sums of deg ----------------
__global__ __launch_bounds__(256) void k_part(const int* __restrict__ deg,
                                              int* __restrict__ part) {
    int i = blockIdx.x * 256 + threadIdx.x;
    int v = (i < NN) ? deg[i] : 0;
    for (int off = 32; off; off >>= 1) v += __shfl_xor(v, off);
    __shared__ int s[4];
    if ((threadIdx.x & 63) == 0) s[threadIdx.x >> 6] = v;
    __syncthreads();
    if (threadIdx.x == 0) part[blockIdx.x] = s[0] + s[1] + s[2] + s[3];
}

// ---------------- scan pass 2: exclusive scan of partials (NB<=512) ----------------
__global__ __launch_bounds__(512) void k_scanpart(int* __restrict__ part) {
    int t = threadIdx.x, lane = t & 63, wv = t >> 6;
    int v0 = (t < NB) ? part[t] : 0;
    int v = v0;
    for (int off = 1; off < 64; off <<= 1) {
        int u = __shfl_up(v, off);
        if (lane >= off) v += u;
    }
    __shared__ int ws[8];
    if (lane == 63) ws[wv] = v;
    __syncthreads();
    if (t == 0) {
        int run = 0;
        for (int w = 0; w < 8; ++w) { int tmp = ws[w]; ws[w] = run; run += tmp; }
    }
    __syncthreads();
    v += ws[wv];
    if (t < NB) part[t] = v - v0;   // exclusive
}

// ---------------- scan pass 3: prefix -> rowptr, cursor; fused dinv ----------------
__global__ __launch_bounds__(256) void k_scan3(const int* __restrict__ deg,
                                               const int* __restrict__ part,
                                               int* __restrict__ rowptr,
                                               int* __restrict__ cursor,
                                               float* __restrict__ dinv) {
    int i = blockIdx.x * 256 + threadIdx.x;
    int lane = threadIdx.x & 63, wv = threadIdx.x >> 6;
    int v0 = (i < NN) ? deg[i] : 0;
    int v = v0;
    for (int off = 1; off < 64; off <<= 1) {
        int u = __shfl_up(v, off);
        if (lane >= off) v += u;
    }
    __shared__ int ws[4], wo[4];
    if (lane == 63) ws[wv] = v;
    __syncthreads();
    if (threadIdx.x == 0) {
        int run = 0;
        for (int w = 0; w < 4; ++w) { int tmp = ws[w]; wo[w] = run; run += tmp; }
    }
    __syncthreads();
    int excl = part[blockIdx.x] + wo[wv] + v - v0;
    if (i < NN) {
        rowptr[i] = excl;
        cursor[i] = excl;
        dinv[i] = rsqrtf((float)(v0 + 1));
    }
}

// ---------------- bucket-fill, XCD-pinned ranges ----------------
// r = blockIdx&7 -> XCD r. Active cursor (50 KB) + csr region (~0.8 MB) live
// in ONE XCD's L2 -> single writeback, no cross-XCD dirty-line duplication.
__global__ __launch_bounds__(256) void k_fillr(const int* __restrict__ src,
                                               const int* __restrict__ dst,
                                               int* __restrict__ cursor,
                                               int* __restrict__ csr_src) {
    int r = blockIdx.x & 7;
    int chunk = blockIdx.x >> 3;
    int lo = r * RSZ8, hi = min(lo + RSZ8, NN);
    int base = chunk * EPB + threadIdx.x;
    #pragma unroll
    for (int i = 0; i < EPB / 256; ++i) {
        int e = base + i * 256;
        if (e < NE) {
            int d = dst[e];
            if (d >= lo && d < hi) {
                int p = atomicAdd(&cursor[d], 1);
                csr_src[p] = src[e];
            }
        }
    }
}

// ---------------- h1s = dinv * (x @ W1)  (N x 256 x 64), fp32 ----------------
// 512 threads, 64 rows/block, lane = row; wave w owns cols [8w,8w+8).
// 32-k chunks (8 barriers), float4 staging, LDS [64][33] (2-way aliasing, free).
__global__ __launch_bounds__(512) void k_gemm1(const float* __restrict__ x,
                                               const float* __restrict__ W1,
                                               const float* __restrict__ dinv,
                                               float* __restrict__ h1s) {
    __shared__ float xs[2][64 * 33];   // 16.9 KB total
    const int t = threadIdx.x;
    const int lane = t & 63;
    const int wvu = __builtin_amdgcn_readfirstlane(t >> 6);
    const int r0 = blockIdx.x * 64;
    const int sr = t >> 3;             // 8 threads per row
    const int sk = (t & 7) * 4;        // float4 each -> 32 floats/row/chunk
    const long xrow = (long)min(r0 + sr, NN - 1) * DI;
    const int row = r0 + lane;

    float acc[8] = {0.f, 0.f, 0.f, 0.f, 0.f, 0.f, 0.f, 0.f};

    {   // stage chunk 0
        float4 v = *(const float4*)(x + xrow + sk);
        float* p = &xs[0][sr * 33 + sk];
        p[0] = v.x; p[1] = v.y; p[2] = v.z; p[3] = v.w;
    }
    __syncthreads();
    for (int c = 0; c < 8; ++c) {
        const int buf = c & 1;
        if (c + 1 < 8) {   // prefetch next 32-k chunk
            float4 v = *(const float4*)(x + xrow + (c + 1) * 32 + sk);
            float* p = &xs[buf ^ 1][sr * 33 + sk];
            p[0] = v.x; p[1] = v.y; p[2] = v.z; p[3] = v.w;
        }
        const f8* wp = (const f8*)(W1) + (size_t)(c * 32) * (DH / 8) + wvu;
        #pragma unroll
        for (int k = 0; k < 32; ++k) {
            float xv = xs[buf][lane * 33 + k];
            f8 w8 = wp[(size_t)k * (DH / 8)];
            #pragma unroll
            for (int j = 0; j < 8; ++j) acc[j] += w8[j] * xv;
        }
        __syncthreads();
    }
    if (row < NN) {
        float di = dinv[row];
        float4 o0 = {di * acc[0], di * acc[1], di * acc[2], di * acc[3]};
        float4 o1 = {di * acc[4], di * acc[5], di * acc[6], di * acc[7]};
        float4* hp = (float4*)(h1s + (long)row * DH + wvu * 8);
        hp[0] = o0;
        hp[1] = o1;
    }
}

// ---------------- layer1 gather (2 rows/wave) + relu/bias + GEMM2 fused ----------------
__global__ __launch_bounds__(256) void k_agg1(const int* __restrict__ rowptr,
                                              const int* __restrict__ deg,
                                              const int* __restrict__ csr_src,
                                              const float* __restrict__ dinv,
                                              const float* __restrict__ h1s,
                                              const float* __restrict__ b1,
                                              const float* __restrict__ W2,
                                              float* __restrict__ h3s) {
    __shared__ float w2[DH * DO];   // 12 KB
    __shared__ float sh[8][DH];     // 2 KB
    for (int i = threadIdx.x; i < DH * DO; i += 256) w2[i] = W2[i];
    __syncthreads();
    const int wv = threadIdx.x >> 6, lane = threadIdx.x & 63;
    const int rA = blockIdx.x * 8 + wv * 2;
    const int rB = rA + 1;
    const int begA = rowptr[rA], cntA = deg[rA];
    const int begB = rowptr[rB], cntB = deg[rB];
    float accA = 0.f, accB = 0.f;
    const int tmax = max(cntA, cntB);
    #pragma unroll 2
    for (int j = 0; j < tmax; j += 4) {
        #pragma unroll
        for (int k = 0; k < 4; ++k) {
            int sa = csr_src[min(begA + j + k, NE - 1)];
            int sb = csr_src[min(begB + j + k, NE - 1)];
            float va = h1s[(size_t)sa * DH + lane];
            float vb = h1s[(size_t)sb * DH + lane];
            accA += (j + k < cntA) ? va : 0.f;
            accB += (j + k < cntB) ? vb : 0.f;
        }
    }
    const float diA = dinv[rA], diB = dinv[rB];
    float vA = diA * (accA + h1s[(size_t)rA * DH + lane]) + b1[lane];
    float vB = diB * (accB + h1s[(size_t)rB * DH + lane]) + b1[lane];
    sh[wv * 2 + 0][lane] = fmaxf(vA, 0.f);
    sh[wv * 2 + 1][lane] = fmaxf(vB, 0.f);
    __syncthreads();
    if (lane < DO) {
        float oA = 0.f, oB = 0.f;
        #pragma unroll 8
        for (int k = 0; k < DH; ++k) {
            float w = w2[k * DO + lane];
            oA += sh[wv * 2 + 0][k] * w;
            oB += sh[wv * 2 + 1][k] * w;
        }
        h3s[(size_t)rA * DH3 + lane] = diA * oA;
        h3s[(size_t)rB * DH3 + lane] = diB * oB;
    }
}

// ---------------- layer2 gather (2 rows/wave) + softmax/argmax fused ----------------
__global__ __launch_bounds__(256) void k_agg2(const int* __restrict__ rowptr,
                                              const int* __restrict__ deg,
                                              const int* __restrict__ csr_src,
                                              const float* __restrict__ dinv,
                                              const float* __restrict__ h3s,
                                              const float* __restrict__ b2,
                                              float* __restrict__ logits,
                                              float* __restrict__ preds,
                                              float* __restrict__ xo) {
    const int wv = threadIdx.x >> 6, lane = threadIdx.x & 63;
    const int rA = blockIdx.x * 8 + wv * 2;
    const int rB = rA + 1;
    const int begA = rowptr[rA], cntA = deg[rA];
    const int begB = rowptr[rB], cntB = deg[rB];
    const bool act = lane < DO;
    const int lx = act ? lane : 0;
    float accA = 0.f, accB = 0.f;
    const int tmax = max(cntA, cntB);
    #pragma unroll 2
    for (int j = 0; j < tmax; j += 4) {
        #pragma unroll
        for (int k = 0; k < 4; ++k) {
            int sa = csr_src[min(begA + j + k, NE - 1)];
            int sb = csr_src[min(begB + j + k, NE - 1)];
            float va = h3s[(size_t)sa * DH3 + lx];
            float vb = h3s[(size_t)sb * DH3 + lx];
            accA += (j + k < cntA) ? va : 0.f;
            accB += (j + k < cntB) ? vb : 0.f;
        }
    }
    const float diA = dinv[rA], diB = dinv[rB];
    float valA = -INFINITY, valB = -INFINITY;
    if (act) {
        valA = diA * (accA + h3s[(size_t)rA * DH3 + lane]) + b2[lane];
        valB = diB * (accB + h3s[(size_t)rB * DH3 + lane]) + b2[lane];
        xo[(size_t)rA * DO + lane] = valA;
        xo[(size_t)rB * DO + lane] = valB;
    }
    float mA = valA, mB = valB;
    for (int off = 32; off; off >>= 1) {
        mA = fmaxf(mA, __shfl_xor(mA, off));
        mB = fmaxf(mB, __shfl_xor(mB, off));
    }
    int idxA = (act && valA == mA) ? lane : (1 << 30);
    int idxB = (act && valB == mB) ? lane : (1 << 30);
    for (int off = 32; off; off >>= 1) {
        idxA = min(idxA, __shfl_xor(idxA, off));
        idxB = min(idxB, __shfl_xor(idxB, off));
    }
    float evA = act ? expf(valA - mA) : 0.f;
    float evB = act ? expf(valB - mB) : 0.f;
    float sA = evA, sB = evB;
    for (int off = 32; off; off >>= 1) {
        sA += __shfl_xor(sA, off);
        sB += __shfl_xor(sB, off);
    }
    if (act) {
        logits[(size_t)rA * DO + lane] = evA / sA;
        logits[(size_t)rB * DO + lane] = evB / sB;
    }
    if (lane == 0) {
        preds[rA] = (float)idxA;
        preds[rB] = (float)idxB;
    }
}

extern "C" void kernel_launch(void* const* d_in, const int* in_sizes, int n_in,
                              void* d_out, int out_size, void* d_ws, size_t ws_size,
                              hipStream_t stream) {
    const float* x  = (const float*)d_in[0];
    const int*   ei = (const int*)d_in[1];
    const float* W1 = (const float*)d_in[2];
    const float* b1 = (const float*)d_in[3];
    const float* W2 = (const float*)d_in[4];
    const float* b2 = (const float*)d_in[5];
    const int* src = ei;          // edge_index[0]
    const int* dst = ei + NE;     // edge_index[1]

    float* out    = (float*)d_out;
    float* logits = out;                      // [N,47]
    float* preds  = out + (size_t)NN * DO;    // [N]
    float* xo     = preds + NN;               // [N,47]

    // workspace layout (~53 MB)
    char* wsb = (char*)d_ws;
    int*   deg     = (int*)wsb;                         wsb += (size_t)NN * 4;
    float* dinv    = (float*)wsb;                       wsb += (size_t)NN * 4;
    int*   rowptr  = (int*)wsb;                         wsb += (size_t)NN * 4;
    int*   cursor  = (int*)wsb;                         wsb += (size_t)NN * 4;
    int*   part    = (int*)wsb;                         wsb += (size_t)512 * 4;
    int*   csr_src = (int*)wsb;                         wsb += (size_t)NE * 4;
    float* h1s     = (float*)wsb;                       wsb += (size_t)NN * DH * 4;
    float* h3s     = (float*)wsb;                       wsb += (size_t)NN * DH3 * 4;

    hipMemsetAsync(deg, 0, NN * sizeof(int), stream);

    k_degree<<<8 * CPB, 256, 0, stream>>>(dst, deg);
    k_part<<<NB, 256, 0, stream>>>(deg, part);
    k_scanpart<<<1, 512, 0, stream>>>(part);
    k_scan3<<<NB, 256, 0, stream>>>(deg, part, rowptr, cursor, dinv);
    k_fillr<<<8 * CPB, 256, 0, stream>>>(src, dst, cursor, csr_src);
    k_gemm1<<<(NN + 63) / 64, 512, 0, stream>>>(x, W1, dinv, h1s);
    k_agg1<<<NN / 8, 256, 0, stream>>>(rowptr, deg, csr_src, dinv, h1s, b1, W2, h3s);
    k_agg2<<<NN / 8, 256, 0, stream>>>(rowptr, deg, csr_src, dinv, h3s, b2, logits, preds, xo);
}